// Round 8
// baseline (249.006 us; speedup 1.0000x reference)
//
#include <hip/hip_runtime.h>
#include <math.h>

// Problem geometry (fixed by setup_inputs)
#define BB   256   // batch
#define DIN  2048  // layer-0 input dim
#define HH   512   // hidden dim
#define NSL  16    // i-slice split
#define GRID 2048  // = (HH/4) * NSL blocks = 8 blocks/CU on 256 CUs

#define NEG_HALF_LOG2E (-0.72134752044448170368f)
#define LOG2E           1.44269504088896340736f
#define LN2             0.69314718055994530942f

typedef float v2f __attribute__((ext_vector_type(2)));

__device__ __forceinline__ float fexp2(float x) { return __builtin_amdgcn_exp2f(x); }
__device__ __forceinline__ float silu_f(float y)
{
    return y * __builtin_amdgcn_rcpf(1.f + fexp2(-y * LOG2E));
}

// VALU-only exp2 (degree-4, |err| ~4e-5 on f in [-0.5,0.5]); z <= 0 here.
// 8 VALU insts: rndne, sub, 4 fma, cvt_i32, ldexp — keeps the trans pipe free.
#define POLY_EXP2(z, dst) {                                   \
    float n_ = __builtin_rintf(z);                            \
    float f_ = (z) - n_;                                      \
    float p_ = fmaf(f_, 0.0096181291f, 0.055504109f);         \
    p_ = fmaf(f_, p_, 0.24022651f);                           \
    p_ = fmaf(f_, p_, 0.69314718f);                           \
    p_ = fmaf(f_, p_, 1.0f);                                  \
    dst = __builtin_ldexpf(p_, (int)n_); }

// ---------------------------------------------------------------------------
// pack one element (o,i) into P[q][g][rr][12] = { r[o0..o3], t*r[o0..o3], w[o0..o3] }
// q=o/4, oo=o%4, g=i/4, rr=i%4.   r = 1/(A_MIN + softplus(s) + 1e-8)
// ---------------------------------------------------------------------------
__device__ __forceinline__ void pack_one(
    const float* __restrict__ s, const float* __restrict__ t,
    const float* __restrict__ w, float* __restrict__ P, int lg, int jj)
{
    int D  = 1 << lg;
    int o  = jj >> lg, i = jj & (D - 1);
    int q  = o >> 2,  oo = o & 3;
    int g  = i >> 2,  rr = i & 3;

    float v  = s[jj];
    float e  = fexp2(-fabsf(v) * LOG2E);
    float sp = fmaxf(v, 0.0f) + LN2 * __builtin_amdgcn_logf(1.0f + e);
    float rv = __builtin_amdgcn_rcpf(0.001f + sp + 1e-8f);

    size_t base = ((size_t)q * (D >> 2) + g) * 48 + rr * 12;
    P[base + oo]     = rv;
    P[base + 4 + oo] = t[jj] * rv;
    P[base + 8 + oo] = w[jj];
}

// ---------------------------------------------------------------------------
// transpose x [BB][DIN] -> x4 [DIN/4][BB] (32x32 tile per block, bid<512)
// ---------------------------------------------------------------------------
__device__ __forceinline__ void transpose_phase(
    const float* __restrict__ in, float4* __restrict__ out4, int bid, int t)
{
    __shared__ float tile[32][33];
    int ct = bid & 63, rt = bid >> 6;          // 64 c-tiles x 8 r-tiles
    int c0 = ct * 32, r0 = rt * 32;
    int tx = t & 31, ty = t >> 5;              // (32, 8)
#pragma unroll
    for (int k = 0; k < 4; k++)
        tile[ty + 8*k][tx] = in[(size_t)(r0 + ty + 8*k) * DIN + c0 + tx];
    __syncthreads();
    float4 v = make_float4(tile[tx][4*ty + 0], tile[tx][4*ty + 1],
                           tile[tx][4*ty + 2], tile[tx][4*ty + 3]);
    out4[(size_t)(c0/4 + ty) * BB + (r0 + tx)] = v;
}

// ---------------------------------------------------------------------------
// wavelet phase: packed f32 math; exp split 50/50 between the transcendental
// pipe (v_exp_f32, ~24 cyc/wave) and a VALU polynomial (~16 cyc/wave) so the
// two pipes work concurrently.  -> atomic accumulate acc[o][b]
// ---------------------------------------------------------------------------
#define WAV_RR(PB, OFF, XSC, POLY) {                              \
    float4 R = *(const float4*)((PB) + (OFF));                    \
    float4 T = *(const float4*)((PB) + (OFF) + 4);                \
    float4 W = *(const float4*)((PB) + (OFF) + 8);                \
    v2f xx  = {(XSC), (XSC)};                                     \
    v2f R01 = {R.x, R.y}, R23 = {R.z, R.w};                       \
    v2f T01 = {T.x, T.y}, T23 = {T.z, T.w};                       \
    v2f W01 = {W.x, W.y}, W23 = {W.z, W.w};                       \
    v2f d01 = __builtin_elementwise_fma(xx, R01, -T01);           \
    v2f d23 = __builtin_elementwise_fma(xx, R23, -T23);           \
    v2f u01 = d01 * d01,  u23 = d23 * d23;                        \
    v2f g01 = u01 * k2,   g23 = u23 * k2;                         \
    v2f e01, e23;                                                 \
    if (POLY) {                                                   \
        POLY_EXP2(g01.x, e01.x); POLY_EXP2(g01.y, e01.y);         \
        POLY_EXP2(g23.x, e23.x); POLY_EXP2(g23.y, e23.y);         \
    } else {                                                      \
        e01.x = fexp2(g01.x); e01.y = fexp2(g01.y);               \
        e23.x = fexp2(g23.x); e23.y = fexp2(g23.y);               \
    }                                                             \
    v2f p01 = __builtin_elementwise_fma(-W01, u01, W01);          \
    v2f p23 = __builtin_elementwise_fma(-W23, u23, W23);          \
    a01 = __builtin_elementwise_fma(p01, e01, a01);               \
    a23 = __builtin_elementwise_fma(p23, e23, a23); }

template<int D>
__device__ __forceinline__ void wav_phase(
    const float4* __restrict__ x4, const float* __restrict__ P,
    float* __restrict__ acc, int q, int sl, int b)
{
    constexpr int G = (D / 4) / NSL;
    const float*  pp = P  + ((size_t)q * (D/4) + (size_t)sl * G) * 48;
    const float4* xp = x4 + (size_t)sl * G * BB + b;

    v2f a01 = {0.f, 0.f}, a23 = {0.f, 0.f};
    const v2f k2 = {NEG_HALF_LOG2E, NEG_HALF_LOG2E};

#pragma unroll 2
    for (int g = 0; g < G; ++g) {
        const float* pb = pp + (size_t)g * 48;
        float4 xv = xp[(size_t)g * BB];
        WAV_RR(pb,  0, xv.x, 0)   // trans pipe
        WAV_RR(pb, 12, xv.y, 0)   // trans pipe
        WAV_RR(pb, 24, xv.z, 1)   // VALU poly
        WAV_RR(pb, 36, xv.w, 1)   // VALU poly
    }

    float* dst = acc + (size_t)(4 * q) * BB + b;
    unsafeAtomicAdd(dst,        a01.x);
    unsafeAtomicAdd(dst + BB,   a01.y);
    unsafeAtomicAdd(dst + 2*BB, a23.x);
    unsafeAtomicAdd(dst + 3*BB, a23.y);
}

// ---------------------------------------------------------------------------
// finish: SiLU + layernorm for batch b; re-zeroes acc column.
// t<128 active; all threads must call (contains __syncthreads).
// ---------------------------------------------------------------------------
__device__ __forceinline__ void finish_phase(
    float* __restrict__ acc, const float* __restrict__ g,
    const float* __restrict__ be, float4* __restrict__ fout4,
    int b, int t)
{
    __shared__ float ls[4];
    float v0 = 0.f, v1 = 0.f, v2 = 0.f, v3 = 0.f;
    if (t < 128) {
        float* ap = acc + (size_t)(4 * t) * BB + b;
        float y0 = ap[0], y1 = ap[BB], y2 = ap[2*BB], y3 = ap[3*BB];
        ap[0] = 0.f; ap[BB] = 0.f; ap[2*BB] = 0.f; ap[3*BB] = 0.f;
        v0 = silu_f(y0); v1 = silu_f(y1); v2 = silu_f(y2); v3 = silu_f(y3);
        float sum = v0 + v1 + v2 + v3;
        float ss  = v0*v0 + v1*v1 + v2*v2 + v3*v3;
#pragma unroll
        for (int off = 32; off; off >>= 1) {
            sum += __shfl_xor(sum, off);
            ss  += __shfl_xor(ss,  off);
        }
        int wid = t >> 6;
        if ((t & 63) == 0) { ls[wid] = sum; ls[2 + wid] = ss; }
    }
    __syncthreads();
    if (t < 128) {
        float sum = ls[0] + ls[1], ss = ls[2] + ls[3];
        float m   = sum * (1.0f / HH);
        float var = ss  * (1.0f / HH) - m * m;
        float rs  = rsqrtf(var + 1e-5f);
        float4 gv = ((const float4*)g)[t];
        float4 bv = ((const float4*)be)[t];
        fout4[(size_t)t * BB + b] = make_float4(gv.x * (v0 - m) * rs + bv.x,
                                                gv.y * (v1 - m) * rs + bv.y,
                                                gv.z * (v2 - m) * rs + bv.z,
                                                gv.w * (v3 - m) * rs + bv.w);
    }
}

// ---------------------------------------------------------------------------
// finish + classifier (layer 2)
// ---------------------------------------------------------------------------
__device__ __forceinline__ void finish_cls_phase(
    const float* __restrict__ acc, const float* __restrict__ g,
    const float* __restrict__ be, const float* __restrict__ cw,
    const float* __restrict__ cb, float* __restrict__ out, int b, int t)
{
    __shared__ float ls[4];
    float v0 = 0.f, v1 = 0.f, v2 = 0.f, v3 = 0.f;
    if (t < 128) {
        const float* ap = acc + (size_t)(4 * t) * BB + b;
        v0 = silu_f(ap[0]); v1 = silu_f(ap[BB]); v2 = silu_f(ap[2*BB]); v3 = silu_f(ap[3*BB]);
        float sum = v0 + v1 + v2 + v3;
        float ss  = v0*v0 + v1*v1 + v2*v2 + v3*v3;
#pragma unroll
        for (int off = 32; off; off >>= 1) {
            sum += __shfl_xor(sum, off);
            ss  += __shfl_xor(ss,  off);
        }
        int wid = t >> 6;
        if ((t & 63) == 0) { ls[wid] = sum; ls[2 + wid] = ss; }
    }
    __syncthreads();
    float c0 = 0.f, c1 = 0.f;
    if (t < 128) {
        float sum = ls[0] + ls[1], ss = ls[2] + ls[3];
        float m  = sum * (1.0f / HH);
        float var = ss * (1.0f / HH) - m * m;
        float rs = rsqrtf(var + 1e-5f);
        float f0 = g[4*t+0] * (v0 - m) * rs + be[4*t+0];
        float f1 = g[4*t+1] * (v1 - m) * rs + be[4*t+1];
        float f2 = g[4*t+2] * (v2 - m) * rs + be[4*t+2];
        float f3 = g[4*t+3] * (v3 - m) * rs + be[4*t+3];
        float4 ca  = ((const float4*)cw)[t];
        float4 cbv = ((const float4*)cw)[HH/4 + t];
        c0 = f0*ca.x  + f1*ca.y  + f2*ca.z  + f3*ca.w;
        c1 = f0*cbv.x + f1*cbv.y + f2*cbv.z + f3*cbv.w;
#pragma unroll
        for (int off = 32; off; off >>= 1) {
            c0 += __shfl_xor(c0, off);
            c1 += __shfl_xor(c1, off);
        }
    }
    __syncthreads();
    if (t < 128 && (t & 63) == 0) { int wid = t >> 6; ls[wid] = c0; ls[2 + wid] = c1; }
    __syncthreads();
    if (t == 0) {
        out[b * 2 + 0] = ls[0] + ls[1] + cb[0];
        out[b * 2 + 1] = ls[2] + ls[3] + cb[1];
    }
}

// ---------------------------------------------------------------------------
// kernels (7 dispatches; kernel boundary = the cheap global sync on MI355X)
// ---------------------------------------------------------------------------
__global__ __launch_bounds__(256, 8) void ph0_k(
    const float* __restrict__ x,
    const float* __restrict__ s0, const float* __restrict__ t0, const float* __restrict__ w0,
    float* __restrict__ P0, float* __restrict__ acc, float4* __restrict__ x4)
{
    int bid = blockIdx.x, t = threadIdx.x;
    int j = bid * 512 + t;
    pack_one(s0, t0, w0, P0, 11, j);
    pack_one(s0, t0, w0, P0, 11, j + 256);
    if (j < HH * BB)       acc[j] = 0.f;
    if (j + 256 < HH * BB) acc[j + 256] = 0.f;
    if (bid < 512) transpose_phase(x, x4, bid, t);
}

template<int D>
__global__ __launch_bounds__(256, 8) void wav_w(
    const float4* __restrict__ x4, const float* __restrict__ P, float* __restrict__ acc)
{
    wav_phase<D>(x4, P, acc, blockIdx.x & (HH/4 - 1), blockIdx.x >> 7, threadIdx.x);
}

__global__ __launch_bounds__(256, 8) void p12f0_k(
    const float* __restrict__ s1, const float* __restrict__ t1, const float* __restrict__ w1,
    const float* __restrict__ s2, const float* __restrict__ t2, const float* __restrict__ w2,
    float* __restrict__ P1, float* __restrict__ P2,
    float* __restrict__ acc, const float* __restrict__ g0,
    const float* __restrict__ b0, float4* __restrict__ fA)
{
    int bid = blockIdx.x, t = threadIdx.x;
    int j = bid * 256 + t;                 // covers 2*HH*HH exactly with GRID blocks
    if (j < HH * HH) pack_one(s1, t1, w1, P1, 9, j);
    else             pack_one(s2, t2, w2, P2, 9, j - HH * HH);
    if (bid < BB) finish_phase(acc, g0, b0, fA, bid, t);
}

__global__ __launch_bounds__(256) void fin_k(
    float* __restrict__ acc, const float* __restrict__ g,
    const float* __restrict__ be, float4* __restrict__ fout4)
{
    finish_phase(acc, g, be, fout4, blockIdx.x, threadIdx.x);
}

__global__ __launch_bounds__(256) void fcls_k(
    const float* __restrict__ acc, const float* __restrict__ g,
    const float* __restrict__ be, const float* __restrict__ cw,
    const float* __restrict__ cb, float* __restrict__ out)
{
    finish_cls_phase(acc, g, be, cw, cb, out, blockIdx.x, threadIdx.x);
}

// ---------------------------------------------------------------------------
extern "C" void kernel_launch(void* const* d_in, const int* in_sizes, int n_in,
                              void* d_out, int out_size, void* d_ws, size_t ws_size,
                              hipStream_t stream)
{
    const float* x  = (const float*)d_in[0];
    const float* t0 = (const float*)d_in[1];
    const float* s0 = (const float*)d_in[2];
    const float* w0 = (const float*)d_in[3];
    const float* g0 = (const float*)d_in[4];
    const float* b0 = (const float*)d_in[5];
    const float* t1 = (const float*)d_in[6];
    const float* s1 = (const float*)d_in[7];
    const float* w1 = (const float*)d_in[8];
    const float* g1 = (const float*)d_in[9];
    const float* b1 = (const float*)d_in[10];
    const float* t2 = (const float*)d_in[11];
    const float* s2 = (const float*)d_in[12];
    const float* w2 = (const float*)d_in[13];
    const float* g2 = (const float*)d_in[14];
    const float* b2 = (const float*)d_in[15];
    const float* cw = (const float*)d_in[16];
    const float* cb = (const float*)d_in[17];
    float* out = (float*)d_out;

    float* ws = (float*)d_ws;
    // workspace (floats), total 3,932,160 = 15.73 MB (proven-safe)
    float*  P0  = ws;                                   // 3,145,728 (P1 aliases P0 after wav0)
    float*  P2  = ws + (size_t)HH * HH * 3;             // inside dead P0 region
    float4* x4  = (float4*)(ws + (size_t)HH * DIN * 3); // 524,288 fl (fB aliases x4)
    float*  acc = ws + (size_t)HH * DIN * 3 + (size_t)(DIN/4) * BB * 4;  // 131,072 fl
    float4* fA  = (float4*)(acc + (size_t)HH * BB);     // 131,072 fl

    ph0_k<<<GRID, 256, 0, stream>>>(x, s0, t0, w0, P0, acc, x4);
    wav_w<DIN><<<GRID, 256, 0, stream>>>(x4, P0, acc);
    p12f0_k<<<GRID, 256, 0, stream>>>(s1, t1, w1, s2, t2, w2, P0, P2, acc, g0, b0, fA);
    wav_w<HH><<<GRID, 256, 0, stream>>>(fA, P0, acc);
    fin_k<<<BB, 256, 0, stream>>>(acc, g1, b1, x4 /*fB*/);
    wav_w<HH><<<GRID, 256, 0, stream>>>((const float4*)x4, P2, acc);
    fcls_k<<<BB, 256, 0, stream>>>(acc, g2, b2, cw, cb, out);
}

// Round 9
// 186.488 us; speedup vs baseline: 1.3352x; 1.3352x over previous
//
#include <hip/hip_runtime.h>
#include <math.h>

// Problem geometry (fixed by setup_inputs)
#define BB   256   // batch
#define DIN  2048  // layer-0 input dim
#define HH   512   // hidden dim
#define NSL  16    // i-slice split -> grid (HH/4, NSL) = 2048 blocks = 8/CU

#define NEG_HALF_LOG2E (-0.72134752044448170368f)
#define LOG2E           1.44269504088896340736f
#define LN2             0.69314718055994530942f

typedef float v2f __attribute__((ext_vector_type(2)));

__device__ __forceinline__ float fexp2(float x) { return __builtin_amdgcn_exp2f(x); }
__device__ __forceinline__ float silu_f(float y)
{
    return y * __builtin_amdgcn_rcpf(1.f + fexp2(-y * LOG2E));
}

// ---------------------------------------------------------------------------
// tz: transpose x [BB][DIN] -> x4 [DIN/4][BB] and zero acc.  grid 512 x 256.
// ---------------------------------------------------------------------------
__global__ __launch_bounds__(256) void tz_k(
    const float* __restrict__ in, float4* __restrict__ out4, float* __restrict__ acc)
{
    __shared__ float tile[32][33];
    int bid = blockIdx.x, t = threadIdx.x;
    acc[bid * 256 + t] = 0.0f;                 // 512*256 == HH*BB exactly
    int ct = bid & 63, rt = bid >> 6;          // 64 c-tiles x 8 r-tiles
    int c0 = ct * 32, r0 = rt * 32;
    int tx = t & 31, ty = t >> 5;              // (32, 8)
#pragma unroll
    for (int k = 0; k < 4; k++)
        tile[ty + 8*k][tx] = in[(size_t)(r0 + ty + 8*k) * DIN + c0 + tx];
    __syncthreads();
    float4 v = make_float4(tile[tx][4*ty + 0], tile[tx][4*ty + 1],
                           tile[tx][4*ty + 2], tile[tx][4*ty + 3]);
    out4[(size_t)(c0/4 + ty) * BB + (r0 + tx)] = v;
}

// ---------------------------------------------------------------------------
// wavelet kernel with in-block param packing into LDS.
// Each block (q, sl): packs its own slice {r, t*r, w} for 4 o-rows x SLICE i's
// into LDS (layout [g][rr][12]), then runs the packed-f32 wavelet loop with
// ds_read params (deeply pipelinable; no SGPR pressure).
// x4: [D/4][BB] float4; acc: [HH][BB] (atomic accumulate)
// ---------------------------------------------------------------------------
#define WAV_RR(PB, OFF, XSC) {                                    \
    float4 R = *(const float4*)((PB) + (OFF));                    \
    float4 T = *(const float4*)((PB) + (OFF) + 4);                \
    float4 W = *(const float4*)((PB) + (OFF) + 8);                \
    v2f xx  = {(XSC), (XSC)};                                     \
    v2f R01 = {R.x, R.y}, R23 = {R.z, R.w};                       \
    v2f T01 = {T.x, T.y}, T23 = {T.z, T.w};                       \
    v2f W01 = {W.x, W.y}, W23 = {W.z, W.w};                       \
    v2f d01 = __builtin_elementwise_fma(xx, R01, -T01);           \
    v2f d23 = __builtin_elementwise_fma(xx, R23, -T23);           \
    v2f u01 = d01 * d01,  u23 = d23 * d23;                        \
    v2f g01 = u01 * k2,   g23 = u23 * k2;                         \
    v2f e01, e23;                                                 \
    e01.x = fexp2(g01.x); e01.y = fexp2(g01.y);                   \
    e23.x = fexp2(g23.x); e23.y = fexp2(g23.y);                   \
    v2f p01 = __builtin_elementwise_fma(-W01, u01, W01);          \
    v2f p23 = __builtin_elementwise_fma(-W23, u23, W23);          \
    a01 = __builtin_elementwise_fma(p01, e01, a01);               \
    a23 = __builtin_elementwise_fma(p23, e23, a23); }

template<int D>
__global__ __launch_bounds__(256, 8) void wav_k(
    const float4* __restrict__ x4,
    const float*  __restrict__ ss,
    const float*  __restrict__ tt,
    const float*  __restrict__ ww,
    float* __restrict__ acc)
{
    constexpr int G     = (D / 4) / NSL;   // g-iters: 32 (L0) or 8 (L1/2)
    constexpr int SLICE = G * 4;           // i's per slice: 128 or 32
    constexpr int LSH   = (SLICE == 128) ? 7 : 5;

    __shared__ float P[G * 48];

    const int q  = blockIdx.x;             // o-quad
    const int sl = blockIdx.y;             // i-slice
    const int t  = threadIdx.x;

    // ---- self-pack param slice into LDS ----
    for (int e = t; e < 4 * SLICE; e += 256) {
        int oo = e >> LSH;                 // 0..3
        int ii = e & (SLICE - 1);
        size_t idx = (size_t)(q * 4 + oo) * D + (size_t)sl * SLICE + ii;
        float v  = ss[idx];
        float e2 = fexp2(-fabsf(v) * LOG2E);
        float sp = fmaxf(v, 0.0f) + LN2 * __builtin_amdgcn_logf(1.0f + e2);
        float rv = __builtin_amdgcn_rcpf(0.001f + sp + 1e-8f);
        int g = ii >> 2, rr = ii & 3;
        P[g * 48 + rr * 12 + 0 + oo] = rv;
        P[g * 48 + rr * 12 + 4 + oo] = tt[idx] * rv;
        P[g * 48 + rr * 12 + 8 + oo] = ww[idx];
    }
    __syncthreads();

    // ---- wavelet loop ----
    const float4* xp = x4 + (size_t)sl * G * BB + t;
    v2f a01 = {0.f, 0.f}, a23 = {0.f, 0.f};
    const v2f k2 = {NEG_HALF_LOG2E, NEG_HALF_LOG2E};

#pragma unroll 2
    for (int g = 0; g < G; ++g) {
        const float* pb = &P[g * 48];
        float4 xv = xp[(size_t)g * BB];
        WAV_RR(pb,  0, xv.x)
        WAV_RR(pb, 12, xv.y)
        WAV_RR(pb, 24, xv.z)
        WAV_RR(pb, 36, xv.w)
    }

    float* dst = acc + (size_t)(4 * q) * BB + t;
    unsafeAtomicAdd(dst,        a01.x);
    unsafeAtomicAdd(dst + BB,   a01.y);
    unsafeAtomicAdd(dst + 2*BB, a23.x);
    unsafeAtomicAdd(dst + 3*BB, a23.y);
}

// ---------------------------------------------------------------------------
// finish: SiLU + layernorm for batch b; re-zeroes acc column.
// grid BB x 256 threads (t<128 active; all threads reach the barrier).
// ---------------------------------------------------------------------------
__global__ __launch_bounds__(256) void fin_k(
    float* __restrict__ acc, const float* __restrict__ g,
    const float* __restrict__ be, float4* __restrict__ fout4)
{
    __shared__ float ls[4];
    const int b = blockIdx.x, t = threadIdx.x;
    float v0 = 0.f, v1 = 0.f, v2 = 0.f, v3 = 0.f;
    if (t < 128) {
        float* ap = acc + (size_t)(4 * t) * BB + b;
        float y0 = ap[0], y1 = ap[BB], y2 = ap[2*BB], y3 = ap[3*BB];
        ap[0] = 0.f; ap[BB] = 0.f; ap[2*BB] = 0.f; ap[3*BB] = 0.f;
        v0 = silu_f(y0); v1 = silu_f(y1); v2 = silu_f(y2); v3 = silu_f(y3);
        float sum = v0 + v1 + v2 + v3;
        float ss  = v0*v0 + v1*v1 + v2*v2 + v3*v3;
#pragma unroll
        for (int off = 32; off; off >>= 1) {
            sum += __shfl_xor(sum, off);
            ss  += __shfl_xor(ss,  off);
        }
        int wid = t >> 6;
        if ((t & 63) == 0) { ls[wid] = sum; ls[2 + wid] = ss; }
    }
    __syncthreads();
    if (t < 128) {
        float sum = ls[0] + ls[1], ss = ls[2] + ls[3];
        float m   = sum * (1.0f / HH);
        float var = ss  * (1.0f / HH) - m * m;
        float rs  = rsqrtf(var + 1e-5f);
        float4 gv = ((const float4*)g)[t];
        float4 bv = ((const float4*)be)[t];
        fout4[(size_t)t * BB + b] = make_float4(gv.x * (v0 - m) * rs + bv.x,
                                                gv.y * (v1 - m) * rs + bv.y,
                                                gv.z * (v2 - m) * rs + bv.z,
                                                gv.w * (v3 - m) * rs + bv.w);
    }
}

// ---------------------------------------------------------------------------
// finish + classifier (layer 2): out[b][c] = sum_o f[o]*cw[c][o] + cb[c]
// ---------------------------------------------------------------------------
__global__ __launch_bounds__(256) void fcls_k(
    const float* __restrict__ acc, const float* __restrict__ g,
    const float* __restrict__ be, const float* __restrict__ cw,
    const float* __restrict__ cb, float* __restrict__ out)
{
    __shared__ float ls[4];
    const int b = blockIdx.x, t = threadIdx.x;
    float v0 = 0.f, v1 = 0.f, v2 = 0.f, v3 = 0.f;
    if (t < 128) {
        const float* ap = acc + (size_t)(4 * t) * BB + b;
        v0 = silu_f(ap[0]); v1 = silu_f(ap[BB]); v2 = silu_f(ap[2*BB]); v3 = silu_f(ap[3*BB]);
        float sum = v0 + v1 + v2 + v3;
        float ss  = v0*v0 + v1*v1 + v2*v2 + v3*v3;
#pragma unroll
        for (int off = 32; off; off >>= 1) {
            sum += __shfl_xor(sum, off);
            ss  += __shfl_xor(ss,  off);
        }
        int wid = t >> 6;
        if ((t & 63) == 0) { ls[wid] = sum; ls[2 + wid] = ss; }
    }
    __syncthreads();
    float c0 = 0.f, c1 = 0.f;
    if (t < 128) {
        float sum = ls[0] + ls[1], ss = ls[2] + ls[3];
        float m  = sum * (1.0f / HH);
        float var = ss * (1.0f / HH) - m * m;
        float rs = rsqrtf(var + 1e-5f);
        float f0 = g[4*t+0] * (v0 - m) * rs + be[4*t+0];
        float f1 = g[4*t+1] * (v1 - m) * rs + be[4*t+1];
        float f2 = g[4*t+2] * (v2 - m) * rs + be[4*t+2];
        float f3 = g[4*t+3] * (v3 - m) * rs + be[4*t+3];
        float4 ca  = ((const float4*)cw)[t];
        float4 cbv = ((const float4*)cw)[HH/4 + t];
        c0 = f0*ca.x  + f1*ca.y  + f2*ca.z  + f3*ca.w;
        c1 = f0*cbv.x + f1*cbv.y + f2*cbv.z + f3*cbv.w;
#pragma unroll
        for (int off = 32; off; off >>= 1) {
            c0 += __shfl_xor(c0, off);
            c1 += __shfl_xor(c1, off);
        }
    }
    __syncthreads();
    if (t < 128 && (t & 63) == 0) { int wid = t >> 6; ls[wid] = c0; ls[2 + wid] = c1; }
    __syncthreads();
    if (t == 0) {
        out[b * 2 + 0] = ls[0] + ls[1] + cb[0];
        out[b * 2 + 1] = ls[2] + ls[3] + cb[1];
    }
}

// ---------------------------------------------------------------------------
extern "C" void kernel_launch(void* const* d_in, const int* in_sizes, int n_in,
                              void* d_out, int out_size, void* d_ws, size_t ws_size,
                              hipStream_t stream)
{
    const float* x  = (const float*)d_in[0];
    const float* t0 = (const float*)d_in[1];
    const float* s0 = (const float*)d_in[2];
    const float* w0 = (const float*)d_in[3];
    const float* g0 = (const float*)d_in[4];
    const float* b0 = (const float*)d_in[5];
    const float* t1 = (const float*)d_in[6];
    const float* s1 = (const float*)d_in[7];
    const float* w1 = (const float*)d_in[8];
    const float* g1 = (const float*)d_in[9];
    const float* b1 = (const float*)d_in[10];
    const float* t2 = (const float*)d_in[11];
    const float* s2 = (const float*)d_in[12];
    const float* w2 = (const float*)d_in[13];
    const float* g2 = (const float*)d_in[14];
    const float* b2 = (const float*)d_in[15];
    const float* cw = (const float*)d_in[16];
    const float* cb = (const float*)d_in[17];
    float* out = (float*)d_out;

    float* ws = (float*)d_ws;
    // workspace (floats): x4 524288 + acc 131072 + fA 131072 = 786,432 fl = 3.1 MB
    float4* x4  = (float4*)ws;                          // [DIN/4][BB]
    float*  acc = ws + (size_t)(DIN/4) * BB * 4;        // [HH][BB]
    float4* fA  = (float4*)(acc + (size_t)HH * BB);     // [HH/4][BB]
    float4* fB  = x4;                                   // reuse x4 (dead after wav0)

    tz_k<<<512, 256, 0, stream>>>(x, x4, acc);

    // ---- layer 0: DIN -> HH ----
    wav_k<DIN><<<dim3(HH/4, NSL), 256, 0, stream>>>(x4, s0, t0, w0, acc);
    fin_k<<<BB, 256, 0, stream>>>(acc, g0, b0, fA);

    // ---- layer 1: HH -> HH ----
    wav_k<HH><<<dim3(HH/4, NSL), 256, 0, stream>>>((const float4*)fA, s1, t1, w1, acc);
    fin_k<<<BB, 256, 0, stream>>>(acc, g1, b1, fB);

    // ---- layer 2: HH -> HH + classifier ----
    wav_k<HH><<<dim3(HH/4, NSL), 256, 0, stream>>>((const float4*)fB, s2, t2, w2, acc);
    fcls_k<<<BB, 256, 0, stream>>>(acc, g2, b2, cw, cb, out);
}